// Round 14
// baseline (198.576 us; speedup 1.0000x reference)
//
#include <hip/hip_runtime.h>
#include <hip/hip_bf16.h>

// RSFConv2d round 14: persistent-column pipelined MFMA conv (R13 + T4 barrier).
//  R13 post-mortem: per-step critical path ~26K cyc vs ~3K of work. Cause:
//  __syncthreads() emits s_waitcnt vmcnt(0) before s_barrier -> every step
//  drains the whole nontemporal-store queue (~64KB/CU/step) INSIDE the
//  barrier, and next step's load retirement queues behind it (vmcnt retires
//  in order). Fix (guide T4): raw s_barrier with lgkmcnt(0) only -- LDS
//  writes must be visible cross-wave, stores are fire-and-forget. Step order
//  becomes: loads(t+1) -> compute -> STORES -> cvt+ds_write -> lgkm-barrier,
//  so each step's stores have a full step to drain before anything waits.
//  Structure otherwise identical to R13 (passed, absmax 1.953e-3):
//  1024 blocks (8n x 16xt x 8yseg XCD-bijective), 64 rows in 8 steps,
//  double-buffered 10-row bands, single-bf16 weights (18 A-frags resident).

typedef __attribute__((ext_vector_type(8))) short bf16x8;
typedef __attribute__((ext_vector_type(16))) float f32x16;
typedef __attribute__((ext_vector_type(4))) unsigned int u32x4;
typedef __attribute__((ext_vector_type(4))) float f32x4v;

__device__ __forceinline__ unsigned short f2bf(float f) {
    unsigned u = __float_as_uint(f);
    u = u + 0x7fffu + ((u >> 16) & 1u);  // RNE
    return (unsigned short)(u >> 16);
}
__device__ __forceinline__ float bf2f(unsigned short b) {
    return __uint_as_float(((unsigned)b) << 16);
}

// lgkm-only barrier: ds_writes visible cross-wave; VMEM (stores/loads) NOT
// drained (T4: never vmcnt(0) in the main loop).
__device__ __forceinline__ void lgkm_barrier() {
    asm volatile("s_waitcnt lgkmcnt(0)" ::: "memory");
    __builtin_amdgcn_s_barrier();
    __builtin_amdgcn_sched_barrier(0);
}

// ---------------- kernel synthesis: one thread per (o,i) pair ----------------
__global__ __launch_bounds__(256) void prep_kernel(const float* __restrict__ fw,
                                                   unsigned short* __restrict__ wbuf)
{
    int gid = blockIdx.x * blockDim.x + threadIdx.x;
    if (gid >= 32 * 32) return;
    int o = gid >> 5;
    int i = gid & 31;

    const float* f = fw + (size_t)gid * 12;
    float re[3][2], im[3][2];
#pragma unroll
    for (int ky = 0; ky < 3; ++ky)
#pragma unroll
        for (int kx = 0; kx < 2; ++kx) {
            re[ky][kx] = f[(ky * 2 + kx) * 2 + 0];
            im[ky][kx] = f[(ky * 2 + kx) * 2 + 1];
        }

    const float c3[3] = {1.f, -0.5f, -0.5f};
    const float s3[3] = {0.f, 0.86602540378443864676f, -0.86602540378443864676f};

    float base[3][3];
#pragma unroll
    for (int y = 0; y < 3; ++y)
#pragma unroll
        for (int x = 0; x < 3; ++x) {
            float sum = 0.f;
#pragma unroll
            for (int ky = 0; ky < 3; ++ky)
#pragma unroll
                for (int kx = 0; kx < 3; ++kx) {
                    float rf, mf;
                    if (kx < 2) {
                        rf = re[ky][kx];
                        mf = im[ky][kx];
                    } else {
                        int kys = (3 - ky) % 3;
                        rf = re[kys][1];
                        mf = -im[kys][1];
                    }
                    int m = (ky * y + kx * x) % 3;
                    sum += rf * c3[m] - mf * s3[m];
                }
            base[y][x] = sum * (1.f / 9.f);
        }

    const float scales[4] = {1.f, 1.25f, 1.5625f, 1.953125f};
    const float coords[3] = {-2.f / 3.f, 0.f, 2.f / 3.f};

    float acc[3][3] = {{0.f, 0.f, 0.f}, {0.f, 0.f, 0.f}, {0.f, 0.f, 0.f}};

    for (int t = 0; t < 32; ++t) {
        int r = t >> 2, si = t & 3;
        float th = (float)r * 0.78539816339744830961f;
        float sc = scales[si];
        float c = cosf(th) * sc;
        float s = sinf(th) * sc;
#pragma unroll
        for (int p = 0; p < 3; ++p) {
#pragma unroll
            for (int q = 0; q < 3; ++q) {
                float gxo = coords[q], gyo = coords[p];
                float gx = c * gxo - s * gyo;
                float gy = s * gxo + c * gyo;
                float ix = ((gx + 1.f) * 3.f - 1.f) * 0.5f;
                float iy = ((gy + 1.f) * 3.f - 1.f) * 0.5f;
                float fx0 = floorf(ix), fy0 = floorf(iy);
                int x0 = (int)fx0, y0 = (int)fy0;
                int x1 = x0 + 1, y1 = y0 + 1;
                float wx1 = ix - fx0, wy1 = iy - fy0;
                float wx0 = 1.f - wx1, wy0 = 1.f - wy1;

                float v = 0.f;
                {
                    int yc = min(max(y0, 0), 2), xc = min(max(x0, 0), 2);
                    bool ok = (x0 >= 0) & (x0 < 3) & (y0 >= 0) & (y0 < 3);
                    v += (ok ? base[yc][xc] : 0.f) * (wy0 * wx0);
                }
                {
                    int yc = min(max(y0, 0), 2), xc = min(max(x1, 0), 2);
                    bool ok = (x1 >= 0) & (x1 < 3) & (y0 >= 0) & (y0 < 3);
                    v += (ok ? base[yc][xc] : 0.f) * (wy0 * wx1);
                }
                {
                    int yc = min(max(y1, 0), 2), xc = min(max(x0, 0), 2);
                    bool ok = (x0 >= 0) & (x0 < 3) & (y1 >= 0) & (y1 < 3);
                    v += (ok ? base[yc][xc] : 0.f) * (wy1 * wx0);
                }
                {
                    int yc = min(max(y1, 0), 2), xc = min(max(x1, 0), 2);
                    bool ok = (x1 >= 0) & (x1 < 3) & (y1 >= 0) & (y1 < 3);
                    v += (ok ? base[yc][xc] : 0.f) * (wy1 * wx1);
                }
                acc[p][q] += v;
            }
        }
    }

    // wbuf[(tap*2+hl)*1024 + o*32 + i]; conv uses hl=0 (wh) only.
#pragma unroll
    for (int p = 0; p < 3; ++p)
#pragma unroll
        for (int q = 0; q < 3; ++q) {
            int t = p * 3 + q;
            float w = acc[p][q] * (1.f / 32.f);
            unsigned short wh = f2bf(w);
            unsigned short wl = f2bf(w - bf2f(wh));
            size_t b = (size_t)(t * 2) * 1024 + o * 32 + i;
            wbuf[b] = wh;
            wbuf[b + 1024] = wl;
        }
}

// ---------------- persistent pipelined conv ----------------
#define ROWB 2176   // 34 px-slots x 64 B (px 0..31 main, 32=left halo, 33=right)
#define BUFB 21760  // 10 rows

// swizzle slot: any 8 consecutive px cover all 8 16B phases
__device__ __forceinline__ unsigned swz(int px, int c) {
    return ((unsigned)px << 6) + ((((unsigned)(px >> 1) & 3u) ^ (unsigned)c) << 4);
}

__global__ __launch_bounds__(256, 2) void conv_pipe(const float* __restrict__ x,
                                                    const unsigned short* __restrict__ wbuf,
                                                    float* __restrict__ out)
{
    __shared__ char lds[2 * BUFB];  // 43520 B

    const int lin = blockIdx.x;     // 1024 blocks: XCD k = image k
    const int n = lin & 7;
    const int idx = lin >> 3;
    const int xt = idx & 15;
    const int yseg = idx >> 4;
    const int x0t = xt * 32;
    const int Y0 = yseg * 64;

    const int tid = threadIdx.x;
    const int lane = tid & 63;
    const int wv = tid >> 6;
    const int pxl = lane & 31;
    const int kh = lane >> 5;

    const float* xn = x + ((size_t)n << 23);

    // ---- A fragments (wh only), loop-invariant: 18 x bf16x8 = 72 VGPR ----
    bf16x8 A[3][3][2];  // [dy][dx][ks]
#pragma unroll
    for (int dy = 0; dy < 3; ++dy)
#pragma unroll
        for (int dx = 0; dx < 3; ++dx)
#pragma unroll
            for (int ks = 0; ks < 2; ++ks)
                A[dy][dx][ks] = *(const bf16x8*)(
                    wbuf + (size_t)((dy * 3 + dx) * 2) * 1024 +
                    pxl * 32 + ks * 16 + kh * 8);

    // ---- per-lane read column offsets (main 0..31, left halo 32, right 33) ----
    int coff[3];
#pragma unroll
    for (int dx = 0; dx < 3; ++dx) {
        int v = dx + pxl - 1;
        int pl = (v < 0) ? 32 : ((v == 32) ? 33 : v);
        coff[dx] = (int)swz(pl, kh);
    }

    // ---- prologue: stage band 0 (gy = Y0-1 .. Y0+8) into BUF0 ----
    for (int u = tid; u < 400; u += 256) {
        if (u < 320) {
            int row = u >> 5, q = (u >> 2) & 7, c = u & 3;
            int gy = Y0 - 1 + row;
            bool ok = (unsigned)gy < 512u;
            const float* src = xn + (((size_t)(c * 8)) << 18) + ((ok ? gy : 0) << 9) +
                               x0t + (q << 2);
            float v[8][4];
#pragma unroll
            for (int cc = 0; cc < 8; ++cc) {
                f32x4v ld = *(const f32x4v*)(src + ((size_t)cc << 18));
#pragma unroll
                for (int j = 0; j < 4; ++j) v[cc][j] = ok ? ld[j] : 0.f;
            }
            int px0 = (q << 2);
#pragma unroll
            for (int j = 0; j < 4; ++j) {
                u32x4 d;
#pragma unroll
                for (int p = 0; p < 4; ++p)
                    d[p] = (unsigned)f2bf(v[2 * p][j]) | ((unsigned)f2bf(v[2 * p + 1][j]) << 16);
                *(u32x4*)(lds + row * ROWB + swz(px0 + j, c)) = d;
            }
        } else {
            int hu = u - 320;
            int row = hu >> 3, side = (hu >> 2) & 1, c = hu & 3;
            int gy = Y0 - 1 + row;
            int gx = x0t + (side ? 32 : -1);
            bool ok = ((unsigned)gy < 512u) & ((unsigned)gx < 512u);
            const float* src = xn + (((size_t)(c * 8)) << 18) +
                               ((ok ? gy : 0) << 9) + (ok ? gx : 0);
            u32x4 d;
#pragma unroll
            for (int p = 0; p < 4; ++p) {
                float a = ok ? src[(size_t)(2 * p) << 18] : 0.f;
                float b = ok ? src[(size_t)(2 * p + 1) << 18] : 0.f;
                d[p] = (unsigned)f2bf(a) | ((unsigned)f2bf(b) << 16);
            }
            *(u32x4*)(lds + row * ROWB + swz(32 + side, c)) = d;
        }
    }
    lgkm_barrier();

    // ---- 8 steps of 8 output rows ----
#pragma unroll 1
    for (int t = 0; t < 8; ++t) {
        const int R = Y0 + (t << 3);
        const bool st = (t < 7);
        const char* rbuf = lds + (t & 1) * BUFB;
        char* wlds = lds + ((t + 1) & 1) * BUFB;

        // -- issue loads for band t+1 (rows gy = R+7 .. R+16) --
        f32x4v L0[8], L1[8];
        float H[8];
        int r0s = 0, q0 = 0, c0 = 0, r1s = 0, q1 = 0, c1 = 0;
        int hr = 0, hside = 0, hc = 0;
        bool ok0 = false, ok1 = false, okh = false;
        const int kind = (tid < 64) ? 1 : (tid < 144 ? 2 : 0);
        if (st) {
            r0s = tid >> 5; q0 = (tid >> 2) & 7; c0 = tid & 3;
            int gy = R + 7 + r0s;
            ok0 = (unsigned)gy < 512u;
            const float* src = xn + (((size_t)(c0 * 8)) << 18) + ((ok0 ? gy : 0) << 9) +
                               x0t + (q0 << 2);
#pragma unroll
            for (int cc = 0; cc < 8; ++cc) L0[cc] = *(const f32x4v*)(src + ((size_t)cc << 18));
            if (kind == 1) {
                int u = 256 + tid;
                r1s = u >> 5; q1 = (u >> 2) & 7; c1 = u & 3;
                int gy1 = R + 7 + r1s;
                ok1 = (unsigned)gy1 < 512u;
                const float* s1 = xn + (((size_t)(c1 * 8)) << 18) + ((ok1 ? gy1 : 0) << 9) +
                                  x0t + (q1 << 2);
#pragma unroll
                for (int cc = 0; cc < 8; ++cc) L1[cc] = *(const f32x4v*)(s1 + ((size_t)cc << 18));
            } else if (kind == 2) {
                int hu = tid - 64;
                hr = hu >> 3; hside = (hu >> 2) & 1; hc = hu & 3;
                int gy1 = R + 7 + hr;
                int gx = x0t + (hside ? 32 : -1);
                okh = ((unsigned)gy1 < 512u) & ((unsigned)gx < 512u);
                const float* s1 = xn + (((size_t)(hc * 8)) << 18) +
                                  ((okh ? gy1 : 0) << 9) + (okh ? gx : 0);
#pragma unroll
                for (int cc = 0; cc < 8; ++cc) H[cc] = s1[(size_t)cc << 18];
            }
        }
        __builtin_amdgcn_sched_barrier(0);  // loads issue BEFORE compute

        // -- compute band t: out rows R+2wv+{0,1} --
        f32x16 acc[2];
#pragma unroll
        for (int f = 0; f < 2; ++f)
#pragma unroll
            for (int r = 0; r < 16; ++r) acc[f][r] = 0.f;

#pragma unroll
        for (int m = 0; m < 4; ++m) {
            const int rs = (wv << 1) + m;  // row slot 0..9
            bf16x8 b[3][2];
#pragma unroll
            for (int dx = 0; dx < 3; ++dx)
#pragma unroll
                for (int ks = 0; ks < 2; ++ks)
                    b[dx][ks] = *(const bf16x8*)(rbuf + rs * ROWB +
                                                 (unsigned)(coff[dx] ^ (ks << 5)));
#pragma unroll
            for (int f = 0; f < 2; ++f) {
                const int dy = m - f;
                if (dy >= 0 && dy < 3) {
#pragma unroll
                    for (int dx = 0; dx < 3; ++dx)
#pragma unroll
                        for (int ks = 0; ks < 2; ++ks)
                            acc[f] = __builtin_amdgcn_mfma_f32_32x32x16_bf16(
                                A[dy][dx][ks], b[dx][ks], acc[f], 0, 0, 0);
                }
            }
        }

        // -- stores FIRST (fire-and-forget; drain across following steps) --
#pragma unroll
        for (int f = 0; f < 2; ++f) {
            int gy = R + (wv << 1) + f;
#pragma unroll
            for (int reg = 0; reg < 16; ++reg) {
                int o = (reg & 3) + 8 * (reg >> 2) + 4 * kh;
                size_t oidx = ((size_t)(n * 32 + o) << 18) + ((size_t)gy << 9) + x0t + pxl;
                __builtin_nontemporal_store(acc[f][reg], &out[oidx]);
            }
        }

        // -- convert + LDS writes for band t+1 (waits only on this step's loads) --
        if (st) {
            {
                int px0 = (q0 << 2);
#pragma unroll
                for (int j = 0; j < 4; ++j) {
                    u32x4 d;
#pragma unroll
                    for (int p = 0; p < 4; ++p) {
                        float a = ok0 ? L0[2 * p][j] : 0.f;
                        float b2 = ok0 ? L0[2 * p + 1][j] : 0.f;
                        d[p] = (unsigned)f2bf(a) | ((unsigned)f2bf(b2) << 16);
                    }
                    *(u32x4*)(wlds + r0s * ROWB + swz(px0 + j, c0)) = d;
                }
            }
            if (kind == 1) {
                int px0 = (q1 << 2);
#pragma unroll
                for (int j = 0; j < 4; ++j) {
                    u32x4 d;
#pragma unroll
                    for (int p = 0; p < 4; ++p) {
                        float a = ok1 ? L1[2 * p][j] : 0.f;
                        float b2 = ok1 ? L1[2 * p + 1][j] : 0.f;
                        d[p] = (unsigned)f2bf(a) | ((unsigned)f2bf(b2) << 16);
                    }
                    *(u32x4*)(wlds + r1s * ROWB + swz(px0 + j, c1)) = d;
                }
            } else if (kind == 2) {
                u32x4 d;
#pragma unroll
                for (int p = 0; p < 4; ++p) {
                    float a = okh ? H[2 * p] : 0.f;
                    float b2 = okh ? H[2 * p + 1] : 0.f;
                    d[p] = (unsigned)f2bf(a) | ((unsigned)f2bf(b2) << 16);
                }
                *(u32x4*)(wlds + hr * ROWB + swz(32 + hside, hc)) = d;
            }
        }

        // -- lgkm-only barrier: LDS visible, VMEM queue NOT drained --
        lgkm_barrier();
    }
}

extern "C" void kernel_launch(void* const* d_in, const int* in_sizes, int n_in,
                              void* d_out, int out_size, void* d_ws, size_t ws_size,
                              hipStream_t stream) {
    const float* x = (const float*)d_in[0];
    const float* fw = (const float*)d_in[1];
    float* out = (float*)d_out;
    unsigned short* wbuf = (unsigned short*)d_ws;  // 18*1024 bf16 = 36864 B

    prep_kernel<<<dim3(4), 256, 0, stream>>>(fw, wbuf);
    conv_pipe<<<dim3(1024), 256, 0, stream>>>(x, wbuf, out);
}

// Round 16
// 189.899 us; speedup vs baseline: 1.0457x; 1.0457x over previous
//
#include <hip/hip_runtime.h>
#include <hip/hip_bf16.h>

// RSFConv2d round 16: persistent-column pipelined MFMA conv.
//  = R13 EXACTLY (proven passing, conv 174us, absmax 1.953e-3) with ONE
//  change: main-loop barrier is lgkmcnt(0) + raw s_barrier + sched_barrier
//  (T4: no vmcnt(0) drain -> the 32 nt-stores issued right before the
//  barrier drain in background instead of stalling all waves ~2-3us/step).
//  Phase ORDER stays R13 (loads -> compute -> cvt+ds_write -> stores ->
//  barrier): vmcnt retires in order, so loads must stay OLDEST in the queue
//  (R14 put stores before cvt and made the load-wait drain stores: -29us).
//  launch_bounds(256,2): R15's (256,3) caused post-timing divergence
//  (suspected compiler pipelining across s_barrier at the higher occupancy
//  target) -- minwaves=3 is poisoned, do not raise it again.

typedef __attribute__((ext_vector_type(8))) short bf16x8;
typedef __attribute__((ext_vector_type(16))) float f32x16;
typedef __attribute__((ext_vector_type(4))) unsigned int u32x4;
typedef __attribute__((ext_vector_type(4))) float f32x4v;

__device__ __forceinline__ unsigned short f2bf(float f) {
    unsigned u = __float_as_uint(f);
    u = u + 0x7fffu + ((u >> 16) & 1u);  // RNE
    return (unsigned short)(u >> 16);
}
__device__ __forceinline__ float bf2f(unsigned short b) {
    return __uint_as_float(((unsigned)b) << 16);
}

// lgkm-only barrier: LDS writes visible cross-wave; VMEM queue not drained.
// R14 ran this barrier through full timing/replay validation: stable.
__device__ __forceinline__ void lgkm_barrier() {
    asm volatile("s_waitcnt lgkmcnt(0)" ::: "memory");
    __builtin_amdgcn_s_barrier();
    __builtin_amdgcn_sched_barrier(0);
}

// ---------------- kernel synthesis: one thread per (o,i) pair ----------------
__global__ __launch_bounds__(256) void prep_kernel(const float* __restrict__ fw,
                                                   unsigned short* __restrict__ wbuf)
{
    int gid = blockIdx.x * blockDim.x + threadIdx.x;
    if (gid >= 32 * 32) return;
    int o = gid >> 5;
    int i = gid & 31;

    const float* f = fw + (size_t)gid * 12;
    float re[3][2], im[3][2];
#pragma unroll
    for (int ky = 0; ky < 3; ++ky)
#pragma unroll
        for (int kx = 0; kx < 2; ++kx) {
            re[ky][kx] = f[(ky * 2 + kx) * 2 + 0];
            im[ky][kx] = f[(ky * 2 + kx) * 2 + 1];
        }

    const float c3[3] = {1.f, -0.5f, -0.5f};
    const float s3[3] = {0.f, 0.86602540378443864676f, -0.86602540378443864676f};

    float base[3][3];
#pragma unroll
    for (int y = 0; y < 3; ++y)
#pragma unroll
        for (int x = 0; x < 3; ++x) {
            float sum = 0.f;
#pragma unroll
            for (int ky = 0; ky < 3; ++ky)
#pragma unroll
                for (int kx = 0; kx < 3; ++kx) {
                    float rf, mf;
                    if (kx < 2) {
                        rf = re[ky][kx];
                        mf = im[ky][kx];
                    } else {
                        int kys = (3 - ky) % 3;
                        rf = re[kys][1];
                        mf = -im[kys][1];
                    }
                    int m = (ky * y + kx * x) % 3;
                    sum += rf * c3[m] - mf * s3[m];
                }
            base[y][x] = sum * (1.f / 9.f);
        }

    const float scales[4] = {1.f, 1.25f, 1.5625f, 1.953125f};
    const float coords[3] = {-2.f / 3.f, 0.f, 2.f / 3.f};

    float acc[3][3] = {{0.f, 0.f, 0.f}, {0.f, 0.f, 0.f}, {0.f, 0.f, 0.f}};

    for (int t = 0; t < 32; ++t) {
        int r = t >> 2, si = t & 3;
        float th = (float)r * 0.78539816339744830961f;
        float sc = scales[si];
        float c = cosf(th) * sc;
        float s = sinf(th) * sc;
#pragma unroll
        for (int p = 0; p < 3; ++p) {
#pragma unroll
            for (int q = 0; q < 3; ++q) {
                float gxo = coords[q], gyo = coords[p];
                float gx = c * gxo - s * gyo;
                float gy = s * gxo + c * gyo;
                float ix = ((gx + 1.f) * 3.f - 1.f) * 0.5f;
                float iy = ((gy + 1.f) * 3.f - 1.f) * 0.5f;
                float fx0 = floorf(ix), fy0 = floorf(iy);
                int x0 = (int)fx0, y0 = (int)fy0;
                int x1 = x0 + 1, y1 = y0 + 1;
                float wx1 = ix - fx0, wy1 = iy - fy0;
                float wx0 = 1.f - wx1, wy0 = 1.f - wy1;

                float v = 0.f;
                {
                    int yc = min(max(y0, 0), 2), xc = min(max(x0, 0), 2);
                    bool ok = (x0 >= 0) & (x0 < 3) & (y0 >= 0) & (y0 < 3);
                    v += (ok ? base[yc][xc] : 0.f) * (wy0 * wx0);
                }
                {
                    int yc = min(max(y0, 0), 2), xc = min(max(x1, 0), 2);
                    bool ok = (x1 >= 0) & (x1 < 3) & (y0 >= 0) & (y0 < 3);
                    v += (ok ? base[yc][xc] : 0.f) * (wy0 * wx1);
                }
                {
                    int yc = min(max(y1, 0), 2), xc = min(max(x0, 0), 2);
                    bool ok = (x0 >= 0) & (x0 < 3) & (y1 >= 0) & (y1 < 3);
                    v += (ok ? base[yc][xc] : 0.f) * (wy1 * wx0);
                }
                {
                    int yc = min(max(y1, 0), 2), xc = min(max(x1, 0), 2);
                    bool ok = (x1 >= 0) & (x1 < 3) & (y1 >= 0) & (y1 < 3);
                    v += (ok ? base[yc][xc] : 0.f) * (wy1 * wx1);
                }
                acc[p][q] += v;
            }
        }
    }

    // wbuf[(tap*2+hl)*1024 + o*32 + i]; conv uses hl=0 (wh) only.
#pragma unroll
    for (int p = 0; p < 3; ++p)
#pragma unroll
        for (int q = 0; q < 3; ++q) {
            int t = p * 3 + q;
            float w = acc[p][q] * (1.f / 32.f);
            unsigned short wh = f2bf(w);
            unsigned short wl = f2bf(w - bf2f(wh));
            size_t b = (size_t)(t * 2) * 1024 + o * 32 + i;
            wbuf[b] = wh;
            wbuf[b + 1024] = wl;
        }
}

// ---------------- persistent pipelined conv ----------------
#define ROWB 2176   // 34 px-slots x 64 B (px 0..31 main, 32=left halo, 33=right)
#define BUFB 21760  // 10 rows

// swizzle slot: any 8 consecutive px cover all 8 16B phases
__device__ __forceinline__ unsigned swz(int px, int c) {
    return ((unsigned)px << 6) + ((((unsigned)(px >> 1) & 3u) ^ (unsigned)c) << 4);
}

__global__ __launch_bounds__(256, 2) void conv_pipe(const float* __restrict__ x,
                                                    const unsigned short* __restrict__ wbuf,
                                                    float* __restrict__ out)
{
    __shared__ char lds[2 * BUFB];  // 43520 B

    const int lin = blockIdx.x;     // 1024 blocks: XCD k = image k
    const int n = lin & 7;
    const int idx = lin >> 3;
    const int xt = idx & 15;
    const int yseg = idx >> 4;
    const int x0t = xt * 32;
    const int Y0 = yseg * 64;

    const int tid = threadIdx.x;
    const int lane = tid & 63;
    const int wv = tid >> 6;
    const int pxl = lane & 31;
    const int kh = lane >> 5;

    const float* xn = x + ((size_t)n << 23);

    // ---- A fragments (wh only), loop-invariant: 18 x bf16x8 = 72 VGPR ----
    bf16x8 A[3][3][2];  // [dy][dx][ks]
#pragma unroll
    for (int dy = 0; dy < 3; ++dy)
#pragma unroll
        for (int dx = 0; dx < 3; ++dx)
#pragma unroll
            for (int ks = 0; ks < 2; ++ks)
                A[dy][dx][ks] = *(const bf16x8*)(
                    wbuf + (size_t)((dy * 3 + dx) * 2) * 1024 +
                    pxl * 32 + ks * 16 + kh * 8);

    // ---- per-lane read column offsets (main 0..31, left halo 32, right 33) ----
    int coff[3];
#pragma unroll
    for (int dx = 0; dx < 3; ++dx) {
        int v = dx + pxl - 1;
        int pl = (v < 0) ? 32 : ((v == 32) ? 33 : v);
        coff[dx] = (int)swz(pl, kh);
    }

    // ---- prologue: stage band 0 (gy = Y0-1 .. Y0+8) into BUF0 ----
    for (int u = tid; u < 400; u += 256) {
        if (u < 320) {
            int row = u >> 5, q = (u >> 2) & 7, c = u & 3;
            int gy = Y0 - 1 + row;
            bool ok = (unsigned)gy < 512u;
            const float* src = xn + (((size_t)(c * 8)) << 18) + ((ok ? gy : 0) << 9) +
                               x0t + (q << 2);
            float v[8][4];
#pragma unroll
            for (int cc = 0; cc < 8; ++cc) {
                f32x4v ld = *(const f32x4v*)(src + ((size_t)cc << 18));
#pragma unroll
                for (int j = 0; j < 4; ++j) v[cc][j] = ok ? ld[j] : 0.f;
            }
            int px0 = (q << 2);
#pragma unroll
            for (int j = 0; j < 4; ++j) {
                u32x4 d;
#pragma unroll
                for (int p = 0; p < 4; ++p)
                    d[p] = (unsigned)f2bf(v[2 * p][j]) | ((unsigned)f2bf(v[2 * p + 1][j]) << 16);
                *(u32x4*)(lds + row * ROWB + swz(px0 + j, c)) = d;
            }
        } else {
            int hu = u - 320;
            int row = hu >> 3, side = (hu >> 2) & 1, c = hu & 3;
            int gy = Y0 - 1 + row;
            int gx = x0t + (side ? 32 : -1);
            bool ok = ((unsigned)gy < 512u) & ((unsigned)gx < 512u);
            const float* src = xn + (((size_t)(c * 8)) << 18) +
                               ((ok ? gy : 0) << 9) + (ok ? gx : 0);
            u32x4 d;
#pragma unroll
            for (int p = 0; p < 4; ++p) {
                float a = ok ? src[(size_t)(2 * p) << 18] : 0.f;
                float b = ok ? src[(size_t)(2 * p + 1) << 18] : 0.f;
                d[p] = (unsigned)f2bf(a) | ((unsigned)f2bf(b) << 16);
            }
            *(u32x4*)(lds + row * ROWB + swz(32 + side, c)) = d;
        }
    }
    lgkm_barrier();

    // ---- 8 steps of 8 output rows ----
#pragma unroll 1
    for (int t = 0; t < 8; ++t) {
        const int R = Y0 + (t << 3);
        const bool st = (t < 7);
        const char* rbuf = lds + (t & 1) * BUFB;
        char* wlds = lds + ((t + 1) & 1) * BUFB;

        // -- issue loads for band t+1 (rows gy = R+7 .. R+16) --
        f32x4v L0[8], L1[8];
        float H[8];
        int r0s = 0, q0 = 0, c0 = 0, r1s = 0, q1 = 0, c1 = 0;
        int hr = 0, hside = 0, hc = 0;
        bool ok0 = false, ok1 = false, okh = false;
        const int kind = (tid < 64) ? 1 : (tid < 144 ? 2 : 0);
        if (st) {
            r0s = tid >> 5; q0 = (tid >> 2) & 7; c0 = tid & 3;
            int gy = R + 7 + r0s;
            ok0 = (unsigned)gy < 512u;
            const float* src = xn + (((size_t)(c0 * 8)) << 18) + ((ok0 ? gy : 0) << 9) +
                               x0t + (q0 << 2);
#pragma unroll
            for (int cc = 0; cc < 8; ++cc) L0[cc] = *(const f32x4v*)(src + ((size_t)cc << 18));
            if (kind == 1) {
                int u = 256 + tid;
                r1s = u >> 5; q1 = (u >> 2) & 7; c1 = u & 3;
                int gy1 = R + 7 + r1s;
                ok1 = (unsigned)gy1 < 512u;
                const float* s1 = xn + (((size_t)(c1 * 8)) << 18) + ((ok1 ? gy1 : 0) << 9) +
                                  x0t + (q1 << 2);
#pragma unroll
                for (int cc = 0; cc < 8; ++cc) L1[cc] = *(const f32x4v*)(s1 + ((size_t)cc << 18));
            } else if (kind == 2) {
                int hu = tid - 64;
                hr = hu >> 3; hside = (hu >> 2) & 1; hc = hu & 3;
                int gy1 = R + 7 + hr;
                int gx = x0t + (hside ? 32 : -1);
                okh = ((unsigned)gy1 < 512u) & ((unsigned)gx < 512u);
                const float* s1 = xn + (((size_t)(hc * 8)) << 18) +
                                  ((okh ? gy1 : 0) << 9) + (okh ? gx : 0);
#pragma unroll
                for (int cc = 0; cc < 8; ++cc) H[cc] = s1[(size_t)cc << 18];
            }
        }
        __builtin_amdgcn_sched_barrier(0);  // loads issue BEFORE compute

        // -- compute band t: out rows R+2wv+{0,1} --
        f32x16 acc[2];
#pragma unroll
        for (int f = 0; f < 2; ++f)
#pragma unroll
            for (int r = 0; r < 16; ++r) acc[f][r] = 0.f;

#pragma unroll
        for (int m = 0; m < 4; ++m) {
            const int rs = (wv << 1) + m;  // row slot 0..9
            bf16x8 b[3][2];
#pragma unroll
            for (int dx = 0; dx < 3; ++dx)
#pragma unroll
                for (int ks = 0; ks < 2; ++ks)
                    b[dx][ks] = *(const bf16x8*)(rbuf + rs * ROWB +
                                                 (unsigned)(coff[dx] ^ (ks << 5)));
#pragma unroll
            for (int f = 0; f < 2; ++f) {
                const int dy = m - f;
                if (dy >= 0 && dy < 3) {
#pragma unroll
                    for (int dx = 0; dx < 3; ++dx)
#pragma unroll
                        for (int ks = 0; ks < 2; ++ks)
                            acc[f] = __builtin_amdgcn_mfma_f32_32x32x16_bf16(
                                A[dy][dx][ks], b[dx][ks], acc[f], 0, 0, 0);
                }
            }
        }

        // -- convert + LDS writes for band t+1 (loads are oldest in vmcnt queue) --
        if (st) {
            {
                int px0 = (q0 << 2);
#pragma unroll
                for (int j = 0; j < 4; ++j) {
                    u32x4 d;
#pragma unroll
                    for (int p = 0; p < 4; ++p) {
                        float a = ok0 ? L0[2 * p][j] : 0.f;
                        float b2 = ok0 ? L0[2 * p + 1][j] : 0.f;
                        d[p] = (unsigned)f2bf(a) | ((unsigned)f2bf(b2) << 16);
                    }
                    *(u32x4*)(wlds + r0s * ROWB + swz(px0 + j, c0)) = d;
                }
            }
            if (kind == 1) {
                int px0 = (q1 << 2);
#pragma unroll
                for (int j = 0; j < 4; ++j) {
                    u32x4 d;
#pragma unroll
                    for (int p = 0; p < 4; ++p) {
                        float a = ok1 ? L1[2 * p][j] : 0.f;
                        float b2 = ok1 ? L1[2 * p + 1][j] : 0.f;
                        d[p] = (unsigned)f2bf(a) | ((unsigned)f2bf(b2) << 16);
                    }
                    *(u32x4*)(wlds + r1s * ROWB + swz(px0 + j, c1)) = d;
                }
            } else if (kind == 2) {
                u32x4 d;
#pragma unroll
                for (int p = 0; p < 4; ++p) {
                    float a = okh ? H[2 * p] : 0.f;
                    float b2 = okh ? H[2 * p + 1] : 0.f;
                    d[p] = (unsigned)f2bf(a) | ((unsigned)f2bf(b2) << 16);
                }
                *(u32x4*)(wlds + hr * ROWB + swz(32 + hside, hc)) = d;
            }
        }

        // -- stores LAST (drain in background across the lgkm-only barrier) --
#pragma unroll
        for (int f = 0; f < 2; ++f) {
            int gy = R + (wv << 1) + f;
#pragma unroll
            for (int reg = 0; reg < 16; ++reg) {
                int o = (reg & 3) + 8 * (reg >> 2) + 4 * kh;
                size_t oidx = ((size_t)(n * 32 + o) << 18) + ((size_t)gy << 9) + x0t + pxl;
                __builtin_nontemporal_store(acc[f][reg], &out[oidx]);
            }
        }

        // -- lgkm-only barrier: LDS visible, VMEM queue NOT drained --
        lgkm_barrier();
    }
}

extern "C" void kernel_launch(void* const* d_in, const int* in_sizes, int n_in,
                              void* d_out, int out_size, void* d_ws, size_t ws_size,
                              hipStream_t stream) {
    const float* x = (const float*)d_in[0];
    const float* fw = (const float*)d_in[1];
    float* out = (float*)d_out;
    unsigned short* wbuf = (unsigned short*)d_ws;  // 18*1024 bf16 = 36864 B

    prep_kernel<<<dim3(4), 256, 0, stream>>>(fw, wbuf);
    conv_pipe<<<dim3(1024), 256, 0, stream>>>(x, wbuf, out);
}